// Round 12
// baseline (193.465 us; speedup 1.0000x reference)
//
#include <hip/hip_runtime.h>
#include <hip/hip_cooperative_groups.h>
namespace cg = cooperative_groups;

// Problem constants
static constexpr int NN = 512, CC = 1000, PP = 256, ORD = 127;

// Workspace layout (bytes), all 8-aligned
static constexpr size_t OFF_TEMPT  = 0;        // PP*CC f32 = 1,024,000
static constexpr size_t OFF_LOGC   = 1024000;  // CC f64
static constexpr size_t OFF_T2     = 1032000;  // CC f64
static constexpr size_t OFF_F2     = 1040000;  // NN f64
static constexpr size_t OFF_LOGITS = 1048576;  // NN*CC f32

// ONE cooperative kernel, 512 blocks x 256 threads (2 blocks/CU -> co-resident).
// Phase A: input-role detection, F2[b], class stats for c = b and b+512 via a
//          matched-sample list (no zeroed accumulators, no global atomics),
//          f32 logc chains on lanes 0-1.
// Phase B: logits. b -> (ct=b&3, nt=b>>2): c = ct*256+tid, 4 samples n0..n0+3.
//          f32 cross-dot vs LDS-staged rows; k=sqrt(T2+2D+F2) f64, f32-rounded;
//          4 interleaved f32 Miller chains; f64 final assembly.
// Phase C: row b normalize -> f32 out.
__global__ __launch_bounds__(256) void k_fused(
    const float* __restrict__ feats, const unsigned* __restrict__ A,
    const unsigned* __restrict__ B, const float* __restrict__ Ave,
    const float* __restrict__ Amount, float* __restrict__ tempT,
    double* __restrict__ logcv, double* __restrict__ T2,
    double* __restrict__ F2, float* __restrict__ logits,
    float* __restrict__ out)
{
    cg::grid_group grid = cg::this_grid();
    const int b = blockIdx.x, tid = threadIdx.x;

    __shared__ float  f_s[4][PP];   // phase B staging (4 KB)
    __shared__ float  red4[4];
    __shared__ double redd[4];
    __shared__ int    s_list[64];
    __shared__ int    s_lcnt;
    __shared__ int    s_fl[2];
    __shared__ float  s_kf[2];

    // ---------------- Phase A ----------------
    if (tid < 2) s_fl[tid] = 0;
    __syncthreads();
    {
        int f0 = 0, f1 = 0;
        for (int w = tid; w < NN; w += 256) {
            if (A[w] > 1u) f0 = 1;
            if (B[w] > 1u) f1 = 1;
        }
        if (f0) atomicOr(&s_fl[0], 1);
        if (f1) atomicOr(&s_fl[1], 1);
    }
    __syncthreads();
    const bool a_is_lab = s_fl[0] ? true : (s_fl[1] ? false : true);
    const unsigned* LAB = a_is_lab ? A : B;
    const unsigned* MSK = a_is_lab ? B : A;

    // F2 for sample n = b
    {
        float v = feats[b * PP + tid];
        double ss = (double)v * (double)v;
        for (int off = 32; off > 0; off >>= 1) ss += __shfl_down(ss, off);
        if ((tid & 63) == 0) redd[tid >> 6] = ss;
        __syncthreads();
        if (tid == 0) F2[b] = redd[0] + redd[1] + redd[2] + redd[3];
        __syncthreads();
    }

    // classes c = b, b+512 (block-uniform branch)
    for (int q = 0; q < 2; ++q) {
        int c = b + q * 512;
        if (c < CC) {
            if (tid == 0) s_lcnt = 0;
            __syncthreads();
            for (int n = tid; n < NN; n += 256) {
                if (MSK[n] != 0u && (int)LAB[n] == c) {
                    int i = atomicAdd(&s_lcnt, 1);
                    if (i < 64) s_list[i] = n;
                }
            }
            __syncthreads();
            int lc = s_lcnt < 64 ? s_lcnt : 64;
            float sum = 0.f;
            for (int i = 0; i < lc; ++i) sum += feats[s_list[i] * PP + tid];
            float cntf = (float)s_lcnt;
            float amount = Amount[c];
            float w = cntf / (cntf + amount);   // 0/0 -> NaN when cnt==0, Amount==0
            if (isnan(w)) w = 0.f;
            float denom = (cntf == 0.f) ? 1.f : cntf;
            float ave = sum / denom;
            float av_new = Ave[c * PP + tid] * (1.f - w) + ave * w;

            float ss = av_new * av_new;
            for (int off = 32; off > 0; off >>= 1) ss += __shfl_down(ss, off);
            if ((tid & 63) == 0) red4[tid >> 6] = ss;
            __syncthreads();
            float tot = red4[0] + red4[1] + red4[2] + red4[3];

            float R = sqrtf(tot);
            float kf = 256.0f * R / (1.0f - R * R);
            if (kf > 1e5f || kf < 0.0f) kf = 1e5f;   // matches reference clamp
            float mu = av_new / fmaxf(R, 1e-12f);
            float tv = kf * mu;                      // f32-round matches reference
            tempT[tid * CC + c] = tv;

            double ts = (double)tv * (double)tv;
            for (int off = 32; off > 0; off >>= 1) ts += __shfl_down(ts, off);
            if ((tid & 63) == 0) redd[tid >> 6] = ts;
            __syncthreads();
            if (tid == 0) {
                T2[c] = redd[0] + redd[1] + redd[2] + redd[3];
                s_kf[q] = kf;
            }
            __syncthreads();
        }
    }
    // f32 logc chains, lanes 0-1 (lockstep, no divergence cost)
    if (tid < 2 && (b + tid * 512) < CC) {
        int c = b + tid * 512;
        float kf = s_kf[tid];
        float invf = 1.0f / kf;
        float In = 1.f, In1 = 0.f, i2 = 508.f;
        for (int it = 0; it < ORD; ++it) {   // i = 254 .. 128
            float t = fmaf(i2 * invf, In, In1); In1 = In; In = t; i2 -= 2.f;
        }
        float E0 = In;
        for (int it = 0; it < ORD; ++it) {   // i = 127 .. 1
            float t = fmaf(i2 * invf, In, In1); In1 = In; In = t; i2 -= 2.f;
        }
        float x = 0.125f * invf;
        float pser = x * (1.f + x * (4.5f + x * (37.5f + x * 459.375f)));
        float l1p = pser - 0.5f * pser * pser;
        float lr = logf(E0 / In);
        float lk = logf(kf);
        logcv[c] = (double)(l1p + lr) - 0.9189385332046727
                   + (double)kf - 127.5 * (double)lk;
    }

    grid.sync();

    // ---------------- Phase B ----------------
    {
        const int ct = b & 3, nt = b >> 2;
        const int c  = ct * 256 + tid;
        const int n0 = nt * 4;
        #pragma unroll
        for (int j = 0; j < 4; ++j)
            f_s[j][tid] = feats[(n0 + j) * PP + tid];
        __syncthreads();
        const bool act = (c < CC);

        float a0 = 0.f, a1 = 0.f, a2 = 0.f, a3 = 0.f;
        if (act) {
            #pragma unroll 4
            for (int a = 0; a < PP; ++a) {
                float tv = tempT[a * CC + c];
                a0 = fmaf(tv, f_s[0][a], a0);
                a1 = fmaf(tv, f_s[1][a], a1);
                a2 = fmaf(tv, f_s[2][a], a2);
                a3 = fmaf(tv, f_s[3][a], a3);
            }
        }
        float accs[4] = {a0, a1, a2, a3};
        double t2c = act ? T2[c] : 1.0e6;
        double kd[4];
        float kf[4], invf[4], In[4], In1[4], E0[4];
        #pragma unroll
        for (int j = 0; j < 4; ++j) {
            double kk = act ? (t2c + 2.0 * (double)accs[j] + F2[n0 + j]) : 1.0e6;
            kd[j]  = (double)(float)sqrt(kk);   // f32-round like reference
            kf[j]  = (float)kd[j];
            invf[j] = 1.0f / kf[j];
            In[j] = 1.f; In1[j] = 0.f;
        }
        float i2 = 508.f;
        for (int it = 0; it < ORD; ++it) {      // i = 254 .. 128
            #pragma unroll
            for (int j = 0; j < 4; ++j) {
                float t = fmaf(i2 * invf[j], In[j], In1[j]);
                In1[j] = In[j]; In[j] = t;
            }
            i2 -= 2.f;
        }
        #pragma unroll
        for (int j = 0; j < 4; ++j) E0[j] = In[j];
        for (int it = 0; it < ORD; ++it) {      // i = 127 .. 1
            #pragma unroll
            for (int j = 0; j < 4; ++j) {
                float t = fmaf(i2 * invf[j], In[j], In1[j]);
                In1[j] = In[j]; In[j] = t;
            }
            i2 -= 2.f;
        }
        if (act) {
            double lgc = logcv[c];
            #pragma unroll
            for (int j = 0; j < 4; ++j) {
                float x = 0.125f * invf[j];
                float pser = x * (1.f + x * (4.5f + x * (37.5f + x * 459.375f)));
                float l1p = pser - 0.5f * pser * pser;
                float lr = logf(E0[j] / In[j]);
                float lk = logf(kf[j]);
                double lg = (double)(l1p + lr) - 0.9189385332046727
                            + kd[j] - 127.5 * (double)lk - lgc;
                logits[(n0 + j) * CC + c] = (float)lg;
            }
        }
    }

    grid.sync();

    // ---------------- Phase C ---------------- row b -> out
    {
        float v[4];
        double ss = 0.0;
        #pragma unroll
        for (int q = 0; q < 4; ++q) {
            int c = tid + q * 256;
            v[q] = (c < CC) ? logits[b * CC + c] : 0.f;
            ss += (double)v[q] * (double)v[q];
        }
        for (int off = 32; off > 0; off >>= 1) ss += __shfl_down(ss, off);
        if ((tid & 63) == 0) redd[tid >> 6] = ss;
        __syncthreads();
        double tot = redd[0] + redd[1] + redd[2] + redd[3];
        float inv = 1.0f / fmaxf((float)sqrt(tot), 1e-12f);
        #pragma unroll
        for (int q = 0; q < 4; ++q) {
            int c = tid + q * 256;
            if (c < CC) out[b * CC + c] = v[q] * inv;
        }
    }
}

extern "C" void kernel_launch(void* const* d_in, const int* in_sizes, int n_in,
                              void* d_out, int out_size, void* d_ws, size_t ws_size,
                              hipStream_t stream) {
    int i_feat = -1, i_ave = -1, i_amt = -1, i5a = -1, i5b = -1;
    for (int i = 0; i < n_in; ++i) {
        int s = in_sizes[i];
        if      (s == NN * PP) i_feat = i;
        else if (s == CC * PP) i_ave  = i;
        else if (s == CC)      i_amt  = i;
        else if (s == NN)      { if (i5a < 0) i5a = i; else i5b = i; }
    }
    if (i_feat < 0 || i_ave < 0 || i_amt < 0 || i5a < 0 || i5b < 0) {
        i_feat = 0; i5a = 1; i5b = 2; i_ave = 3; i_amt = 4;  // documented order
    }
    const float*    feats  = (const float*)d_in[i_feat];
    const unsigned* bufA   = (const unsigned*)d_in[i5a];
    const unsigned* bufB   = (const unsigned*)d_in[i5b];
    const float*    Ave    = (const float*)d_in[i_ave];
    const float*    Amount = (const float*)d_in[i_amt];

    char* ws = (char*)d_ws;
    float*  tempT  = (float*)(ws + OFF_TEMPT);
    double* logcv  = (double*)(ws + OFF_LOGC);
    double* T2     = (double*)(ws + OFF_T2);
    double* F2     = (double*)(ws + OFF_F2);
    float*  logits = (float*)(ws + OFF_LOGITS);
    float*  out    = (float*)d_out;

    void* args[] = { (void*)&feats, (void*)&bufA, (void*)&bufB, (void*)&Ave,
                     (void*)&Amount, (void*)&tempT, (void*)&logcv, (void*)&T2,
                     (void*)&F2, (void*)&logits, (void*)&out };
    hipLaunchCooperativeKernel(reinterpret_cast<void*>(k_fused),
                               dim3(NN), dim3(256), args, 0, stream);
}

// Round 13
// 105.884 us; speedup vs baseline: 1.8271x; 1.8271x over previous
//
#include <hip/hip_runtime.h>

// Problem constants
static constexpr int NN = 512, CC = 1000, PP = 256, ORD = 127;

// Workspace layout (bytes), all 8-aligned
static constexpr size_t OFF_TEMPT  = 0;        // PP*CC f32 = 1,024,000
static constexpr size_t OFF_LOGC   = 1024000;  // CC f64
static constexpr size_t OFF_T2     = 1032000;  // CC f64
static constexpr size_t OFF_F2     = 1040000;  // NN f64
static constexpr size_t OFF_LOGITS = 1048576;  // NN*CC f32

// Kernel 1: one block per class c (1000 blocks).
//  - input-role detection by value (labels contain >1)
//  - class stats via matched-sample list (LDS atomic list; no global atomics,
//    no zeroing pass): sum ~0-5 matching rows, then Ave update -> temp^T, T2
//  - lane 0: f32 Miller chain -> logc[c]  (f32 error ~1e-5 abs, budget 8e-3)
//  - blocks b < NN additionally compute F2[b] (f64 row sumsq)
__global__ __launch_bounds__(256) void k_prep(
    const float* __restrict__ feats, const unsigned* __restrict__ A,
    const unsigned* __restrict__ B, const float* __restrict__ Ave,
    const float* __restrict__ Amount, float* __restrict__ tempT,
    double* __restrict__ logcv, double* __restrict__ T2,
    double* __restrict__ F2)
{
    __shared__ float  red4[4];
    __shared__ double redd[4];
    __shared__ int    s_list[64];
    __shared__ int    s_lcnt, s_fl0, s_fl1;
    const int c = blockIdx.x, tid = threadIdx.x;

    if (tid == 0) { s_lcnt = 0; s_fl0 = 0; s_fl1 = 0; }
    __syncthreads();
    int f0 = 0, f1 = 0;
    for (int w = tid; w < NN; w += 256) {
        if (A[w] > 1u) f0 = 1;
        if (B[w] > 1u) f1 = 1;
    }
    if (f0) atomicOr(&s_fl0, 1);
    if (f1) atomicOr(&s_fl1, 1);
    __syncthreads();
    const bool a_is_lab = s_fl0 ? true : (s_fl1 ? false : true);
    const unsigned* LAB = a_is_lab ? A : B;
    const unsigned* MSK = a_is_lab ? B : A;

    // F2 for sample n = c (blocks 0..511 only)
    if (c < NN) {
        float v = feats[c * PP + tid];
        double ss = (double)v * (double)v;
        for (int off = 32; off > 0; off >>= 1) ss += __shfl_down(ss, off);
        if ((tid & 63) == 0) redd[tid >> 6] = ss;
        __syncthreads();
        if (tid == 0) F2[c] = redd[0] + redd[1] + redd[2] + redd[3];
        __syncthreads();
    }

    // matched-sample list for class c
    for (int n = tid; n < NN; n += 256) {
        if (MSK[n] != 0u && (int)LAB[n] == c) {
            int i = atomicAdd(&s_lcnt, 1);
            if (i < 64) s_list[i] = n;
        }
    }
    __syncthreads();
    const int lc = s_lcnt < 64 ? s_lcnt : 64;
    float sum = 0.f;
    for (int i = 0; i < lc; ++i) sum += feats[s_list[i] * PP + tid];

    float cntf   = (float)s_lcnt;
    float amount = Amount[c];
    float w = cntf / (cntf + amount);        // 0/0 -> NaN when cnt==0, Amount==0
    if (isnan(w)) w = 0.f;
    float denom = (cntf == 0.f) ? 1.f : cntf;
    float ave = sum / denom;
    float av_new = Ave[c * PP + tid] * (1.f - w) + ave * w;

    float ss2 = av_new * av_new;
    for (int off = 32; off > 0; off >>= 1) ss2 += __shfl_down(ss2, off);
    if ((tid & 63) == 0) red4[tid >> 6] = ss2;
    __syncthreads();
    float tot = red4[0] + red4[1] + red4[2] + red4[3];

    float R = sqrtf(tot);
    float kf = 256.0f * R / (1.0f - R * R);
    if (kf > 1e5f || kf < 0.0f) kf = 1e5f;   // matches reference clamp
    float mu = av_new / fmaxf(R, 1e-12f);
    float tv = kf * mu;                      // f32 rounding matches reference temp
    tempT[tid * CC + c] = tv;

    double ts = (double)tv * (double)tv;
    for (int off = 32; off > 0; off >>= 1) ts += __shfl_down(ts, off);
    if ((tid & 63) == 0) redd[tid >> 6] = ts;
    __syncthreads();

    if (tid == 0) {
        T2[c] = redd[0] + redd[1] + redd[2] + redd[3];
        // f32 Miller chain for logc (self-damping; ~1e-5 abs on log terms)
        float invf = 1.0f / kf;
        float In = 1.f, In1 = 0.f, i2 = 508.f;
        for (int it = 0; it < ORD; ++it) {   // i = 254 .. 128
            float t = fmaf(i2 * invf, In, In1); In1 = In; In = t; i2 -= 2.f;
        }
        float E0 = In;
        for (int it = 0; it < ORD; ++it) {   // i = 127 .. 1
            float t = fmaf(i2 * invf, In, In1); In1 = In; In = t; i2 -= 2.f;
        }
        float x = 0.125f * invf;
        float pser = x * (1.f + x * (4.5f + x * (37.5f + x * 459.375f)));
        float l1p = pser - 0.5f * pser * pser;          // log1p, p ~ 1e-4
        float lr = logf(E0 / In);
        float lk = logf(kf);
        logcv[c] = (double)(l1p + lr) - 0.9189385332046727
                   + (double)kf - 127.5 * (double)lk;
    }
}

// Kernel 2: main logits (identical to R11's proven k_main).
// grid (4 c-tiles, 128 n-tiles of 4). Per thread: one c, 4 n's.
__global__ __launch_bounds__(256) void k_main(
    const float* __restrict__ feats, const float* __restrict__ tempT,
    const double* __restrict__ T2, const double* __restrict__ F2,
    const double* __restrict__ logcv, float* __restrict__ logits)
{
    __shared__ float f_s[4][PP];
    const int tid = threadIdx.x;
    const int n0  = blockIdx.y * 4;
    const int c   = blockIdx.x * 256 + tid;
    #pragma unroll
    for (int j = 0; j < 4; ++j)
        f_s[j][tid] = feats[(n0 + j) * PP + tid];
    __syncthreads();
    const bool act = (c < CC);

    float a0 = 0.f, a1 = 0.f, a2 = 0.f, a3 = 0.f;
    if (act) {
        #pragma unroll 4
        for (int a = 0; a < PP; ++a) {
            float tv = tempT[a * CC + c];
            a0 = fmaf(tv, f_s[0][a], a0);
            a1 = fmaf(tv, f_s[1][a], a1);
            a2 = fmaf(tv, f_s[2][a], a2);
            a3 = fmaf(tv, f_s[3][a], a3);
        }
    }
    float accs[4] = {a0, a1, a2, a3};
    double t2c = act ? T2[c] : 1.0e6;
    double kd[4];
    float kf[4], invf[4], In[4], In1[4], E0[4];
    #pragma unroll
    for (int j = 0; j < 4; ++j) {
        double kk = act ? (t2c + 2.0 * (double)accs[j] + F2[n0 + j]) : 1.0e6;
        kd[j]  = (double)(float)sqrt(kk);   // f32-round like reference kappa_new
        kf[j]  = (float)kd[j];
        invf[j] = 1.0f / kf[j];
        In[j] = 1.f; In1[j] = 0.f;
    }
    float i2 = 508.f;                       // exact f32 integer arithmetic
    for (int it = 0; it < ORD; ++it) {      // i = 254 .. 128
        #pragma unroll
        for (int j = 0; j < 4; ++j) {
            float t = fmaf(i2 * invf[j], In[j], In1[j]);
            In1[j] = In[j]; In[j] = t;
        }
        i2 -= 2.f;
    }
    #pragma unroll
    for (int j = 0; j < 4; ++j) E0[j] = In[j];
    for (int it = 0; it < ORD; ++it) {      // i = 127 .. 1
        #pragma unroll
        for (int j = 0; j < 4; ++j) {
            float t = fmaf(i2 * invf[j], In[j], In1[j]);
            In1[j] = In[j]; In[j] = t;
        }
        i2 -= 2.f;
    }
    if (!act) return;
    double lgc = logcv[c];
    #pragma unroll
    for (int j = 0; j < 4; ++j) {
        float x = 0.125f * invf[j];
        float pser = x * (1.f + x * (4.5f + x * (37.5f + x * 459.375f)));
        float l1p = pser - 0.5f * pser * pser;
        float lr = logf(E0[j] / In[j]);
        float lk = logf(kf[j]);
        double lg = (double)(l1p + lr) - 0.9189385332046727
                    + kd[j] - 127.5 * (double)lk - lgc;
        logits[(n0 + j) * CC + c] = (float)lg;
    }
}

// Kernel 3: row-normalize -> f32 output
__global__ __launch_bounds__(256) void k_norm(
    const float* __restrict__ logits, float* __restrict__ out)
{
    __shared__ double red4[4];
    const int n = blockIdx.x;
    const int tid = threadIdx.x;
    float v[4];
    double ss = 0.0;
    #pragma unroll
    for (int q = 0; q < 4; ++q) {
        int c = tid + q * 256;
        v[q] = (c < CC) ? logits[n * CC + c] : 0.f;
        ss += (double)v[q] * (double)v[q];
    }
    for (int off = 32; off > 0; off >>= 1) ss += __shfl_down(ss, off);
    if ((tid & 63) == 0) red4[tid >> 6] = ss;
    __syncthreads();
    double tot = red4[0] + red4[1] + red4[2] + red4[3];
    float inv = 1.0f / fmaxf((float)sqrt(tot), 1e-12f);
    #pragma unroll
    for (int q = 0; q < 4; ++q) {
        int c = tid + q * 256;
        if (c < CC) out[n * CC + c] = v[q] * inv;
    }
}

extern "C" void kernel_launch(void* const* d_in, const int* in_sizes, int n_in,
                              void* d_out, int out_size, void* d_ws, size_t ws_size,
                              hipStream_t stream) {
    int i_feat = -1, i_ave = -1, i_amt = -1, i5a = -1, i5b = -1;
    for (int i = 0; i < n_in; ++i) {
        int s = in_sizes[i];
        if      (s == NN * PP) i_feat = i;
        else if (s == CC * PP) i_ave  = i;
        else if (s == CC)      i_amt  = i;
        else if (s == NN)      { if (i5a < 0) i5a = i; else i5b = i; }
    }
    if (i_feat < 0 || i_ave < 0 || i_amt < 0 || i5a < 0 || i5b < 0) {
        i_feat = 0; i5a = 1; i5b = 2; i_ave = 3; i_amt = 4;  // documented order
    }
    const float*    feats  = (const float*)d_in[i_feat];
    const unsigned* bufA   = (const unsigned*)d_in[i5a];
    const unsigned* bufB   = (const unsigned*)d_in[i5b];
    const float*    Ave    = (const float*)d_in[i_ave];
    const float*    Amount = (const float*)d_in[i_amt];

    char* ws = (char*)d_ws;
    float*  tempT  = (float*)(ws + OFF_TEMPT);
    double* logcv  = (double*)(ws + OFF_LOGC);
    double* T2     = (double*)(ws + OFF_T2);
    double* F2     = (double*)(ws + OFF_F2);
    float*  logits = (float*)(ws + OFF_LOGITS);
    float*  out    = (float*)d_out;

    k_prep<<<dim3(CC), dim3(256), 0, stream>>>(feats, bufA, bufB, Ave, Amount,
                                               tempT, logcv, T2, F2);
    k_main<<<dim3(4, NN / 4), dim3(256), 0, stream>>>(feats, tempT, T2, F2,
                                                      logcv, logits);
    k_norm<<<dim3(NN), dim3(256), 0, stream>>>(logits, out);
}

// Round 14
// 97.108 us; speedup vs baseline: 1.9923x; 1.0904x over previous
//
#include <hip/hip_runtime.h>

// Problem constants
static constexpr int NN = 512, CC = 1000, PP = 256, ORD = 127;

// Workspace layout (bytes), all 8-aligned
static constexpr size_t OFF_TEMPT  = 0;        // PP*CC f32 = 1,024,000
static constexpr size_t OFF_LOGC   = 1024000;  // CC f64
static constexpr size_t OFF_T2     = 1032000;  // CC f64
static constexpr size_t OFF_F2     = 1040000;  // NN f64
static constexpr size_t OFF_LOGITS = 1048576;  // NN*CC f32

// Kernel 1: one block per class c (1000 blocks). Unchanged from R13.
__global__ __launch_bounds__(256) void k_prep(
    const float* __restrict__ feats, const unsigned* __restrict__ A,
    const unsigned* __restrict__ B, const float* __restrict__ Ave,
    const float* __restrict__ Amount, float* __restrict__ tempT,
    double* __restrict__ logcv, double* __restrict__ T2,
    double* __restrict__ F2)
{
    __shared__ float  red4[4];
    __shared__ double redd[4];
    __shared__ int    s_list[64];
    __shared__ int    s_lcnt, s_fl0, s_fl1;
    const int c = blockIdx.x, tid = threadIdx.x;

    if (tid == 0) { s_lcnt = 0; s_fl0 = 0; s_fl1 = 0; }
    __syncthreads();
    int f0 = 0, f1 = 0;
    for (int w = tid; w < NN; w += 256) {
        if (A[w] > 1u) f0 = 1;
        if (B[w] > 1u) f1 = 1;
    }
    if (f0) atomicOr(&s_fl0, 1);
    if (f1) atomicOr(&s_fl1, 1);
    __syncthreads();
    const bool a_is_lab = s_fl0 ? true : (s_fl1 ? false : true);
    const unsigned* LAB = a_is_lab ? A : B;
    const unsigned* MSK = a_is_lab ? B : A;

    if (c < NN) {   // F2 for sample n = c
        float v = feats[c * PP + tid];
        double ss = (double)v * (double)v;
        for (int off = 32; off > 0; off >>= 1) ss += __shfl_down(ss, off);
        if ((tid & 63) == 0) redd[tid >> 6] = ss;
        __syncthreads();
        if (tid == 0) F2[c] = redd[0] + redd[1] + redd[2] + redd[3];
        __syncthreads();
    }

    for (int n = tid; n < NN; n += 256) {
        if (MSK[n] != 0u && (int)LAB[n] == c) {
            int i = atomicAdd(&s_lcnt, 1);
            if (i < 64) s_list[i] = n;
        }
    }
    __syncthreads();
    const int lc = s_lcnt < 64 ? s_lcnt : 64;
    float sum = 0.f;
    for (int i = 0; i < lc; ++i) sum += feats[s_list[i] * PP + tid];

    float cntf   = (float)s_lcnt;
    float amount = Amount[c];
    float w = cntf / (cntf + amount);        // 0/0 -> NaN when cnt==0, Amount==0
    if (isnan(w)) w = 0.f;
    float denom = (cntf == 0.f) ? 1.f : cntf;
    float ave = sum / denom;
    float av_new = Ave[c * PP + tid] * (1.f - w) + ave * w;

    float ss2 = av_new * av_new;
    for (int off = 32; off > 0; off >>= 1) ss2 += __shfl_down(ss2, off);
    if ((tid & 63) == 0) red4[tid >> 6] = ss2;
    __syncthreads();
    float tot = red4[0] + red4[1] + red4[2] + red4[3];

    float R = sqrtf(tot);
    float kf = 256.0f * R / (1.0f - R * R);
    if (kf > 1e5f || kf < 0.0f) kf = 1e5f;   // matches reference clamp
    float mu = av_new / fmaxf(R, 1e-12f);
    float tv = kf * mu;                      // f32 rounding matches reference temp
    tempT[tid * CC + c] = tv;

    double ts = (double)tv * (double)tv;
    for (int off = 32; off > 0; off >>= 1) ts += __shfl_down(ts, off);
    if ((tid & 63) == 0) redd[tid >> 6] = ts;
    __syncthreads();

    if (tid == 0) {
        T2[c] = redd[0] + redd[1] + redd[2] + redd[3];
        float invf = 1.0f / kf;
        float In = 1.f, In1 = 0.f, i2 = 508.f;
        for (int it = 0; it < ORD; ++it) {   // i = 254 .. 128
            float t = fmaf(i2 * invf, In, In1); In1 = In; In = t; i2 -= 2.f;
        }
        float E0 = In;
        for (int it = 0; it < ORD; ++it) {   // i = 127 .. 1
            float t = fmaf(i2 * invf, In, In1); In1 = In; In = t; i2 -= 2.f;
        }
        float x = 0.125f * invf;
        float pser = x * (1.f + x * (4.5f + x * (37.5f + x * 459.375f)));
        float l1p = pser - 0.5f * pser * pser;          // log1p, p ~ 1e-4
        float lr = logf(E0 / In);
        float lk = logf(kf);
        logcv[c] = (double)(l1p + lr) - 0.9189385332046727
                   + (double)kf - 127.5 * (double)lk;
    }
}

// Kernel 2: main logits. Grid (4 c-tiles, 256 n-tiles of 2): 1024 blocks ->
// 4 blocks/CU = 4 waves/SIMD (was 2) for latency hiding; 2 interleaved chains;
// dot loop unroll 8 for deep load pipelining.
__global__ __launch_bounds__(256) void k_main(
    const float* __restrict__ feats, const float* __restrict__ tempT,
    const double* __restrict__ T2, const double* __restrict__ F2,
    const double* __restrict__ logcv, float* __restrict__ logits)
{
    __shared__ float f_s[2][PP];
    const int tid = threadIdx.x;
    const int n0  = blockIdx.y * 2;
    const int c   = blockIdx.x * 256 + tid;
    #pragma unroll
    for (int j = 0; j < 2; ++j)
        f_s[j][tid] = feats[(n0 + j) * PP + tid];
    __syncthreads();
    const bool act = (c < CC);

    float a0 = 0.f, a1 = 0.f;
    if (act) {
        #pragma unroll 8
        for (int a = 0; a < PP; ++a) {
            float tv = tempT[a * CC + c];
            a0 = fmaf(tv, f_s[0][a], a0);
            a1 = fmaf(tv, f_s[1][a], a1);
        }
    }
    float accs[2] = {a0, a1};
    double t2c = act ? T2[c] : 1.0e6;
    double kd[2];
    float kf[2], invf[2], In[2], In1[2], E0[2];
    #pragma unroll
    for (int j = 0; j < 2; ++j) {
        double kk = act ? (t2c + 2.0 * (double)accs[j] + F2[n0 + j]) : 1.0e6;
        kd[j]  = (double)(float)sqrt(kk);   // f32-round like reference kappa_new
        kf[j]  = (float)kd[j];
        invf[j] = 1.0f / kf[j];
        In[j] = 1.f; In1[j] = 0.f;
    }
    float i2 = 508.f;                       // exact f32 integer arithmetic
    for (int it = 0; it < ORD; ++it) {      // i = 254 .. 128
        #pragma unroll
        for (int j = 0; j < 2; ++j) {
            float t = fmaf(i2 * invf[j], In[j], In1[j]);
            In1[j] = In[j]; In[j] = t;
        }
        i2 -= 2.f;
    }
    #pragma unroll
    for (int j = 0; j < 2; ++j) E0[j] = In[j];
    for (int it = 0; it < ORD; ++it) {      // i = 127 .. 1
        #pragma unroll
        for (int j = 0; j < 2; ++j) {
            float t = fmaf(i2 * invf[j], In[j], In1[j]);
            In1[j] = In[j]; In[j] = t;
        }
        i2 -= 2.f;
    }
    if (!act) return;
    double lgc = logcv[c];
    #pragma unroll
    for (int j = 0; j < 2; ++j) {
        float x = 0.125f * invf[j];
        float pser = x * (1.f + x * (4.5f + x * (37.5f + x * 459.375f)));
        float l1p = pser - 0.5f * pser * pser;
        float lr = logf(E0[j] / In[j]);
        float lk = logf(kf[j]);
        double lg = (double)(l1p + lr) - 0.9189385332046727
                    + kd[j] - 127.5 * (double)lk - lgc;
        logits[(n0 + j) * CC + c] = (float)lg;
    }
}

// Kernel 3: row-normalize -> f32 output (unchanged)
__global__ __launch_bounds__(256) void k_norm(
    const float* __restrict__ logits, float* __restrict__ out)
{
    __shared__ double red4[4];
    const int n = blockIdx.x;
    const int tid = threadIdx.x;
    float v[4];
    double ss = 0.0;
    #pragma unroll
    for (int q = 0; q < 4; ++q) {
        int c = tid + q * 256;
        v[q] = (c < CC) ? logits[n * CC + c] : 0.f;
        ss += (double)v[q] * (double)v[q];
    }
    for (int off = 32; off > 0; off >>= 1) ss += __shfl_down(ss, off);
    if ((tid & 63) == 0) red4[tid >> 6] = ss;
    __syncthreads();
    double tot = red4[0] + red4[1] + red4[2] + red4[3];
    float inv = 1.0f / fmaxf((float)sqrt(tot), 1e-12f);
    #pragma unroll
    for (int q = 0; q < 4; ++q) {
        int c = tid + q * 256;
        if (c < CC) out[n * CC + c] = v[q] * inv;
    }
}

extern "C" void kernel_launch(void* const* d_in, const int* in_sizes, int n_in,
                              void* d_out, int out_size, void* d_ws, size_t ws_size,
                              hipStream_t stream) {
    int i_feat = -1, i_ave = -1, i_amt = -1, i5a = -1, i5b = -1;
    for (int i = 0; i < n_in; ++i) {
        int s = in_sizes[i];
        if      (s == NN * PP) i_feat = i;
        else if (s == CC * PP) i_ave  = i;
        else if (s == CC)      i_amt  = i;
        else if (s == NN)      { if (i5a < 0) i5a = i; else i5b = i; }
    }
    if (i_feat < 0 || i_ave < 0 || i_amt < 0 || i5a < 0 || i5b < 0) {
        i_feat = 0; i5a = 1; i5b = 2; i_ave = 3; i_amt = 4;  // documented order
    }
    const float*    feats  = (const float*)d_in[i_feat];
    const unsigned* bufA   = (const unsigned*)d_in[i5a];
    const unsigned* bufB   = (const unsigned*)d_in[i5b];
    const float*    Ave    = (const float*)d_in[i_ave];
    const float*    Amount = (const float*)d_in[i_amt];

    char* ws = (char*)d_ws;
    float*  tempT  = (float*)(ws + OFF_TEMPT);
    double* logcv  = (double*)(ws + OFF_LOGC);
    double* T2     = (double*)(ws + OFF_T2);
    double* F2     = (double*)(ws + OFF_F2);
    float*  logits = (float*)(ws + OFF_LOGITS);
    float*  out    = (float*)d_out;

    k_prep<<<dim3(CC), dim3(256), 0, stream>>>(feats, bufA, bufB, Ave, Amount,
                                               tempT, logcv, T2, F2);
    k_main<<<dim3(4, NN / 2), dim3(256), 0, stream>>>(feats, tempT, T2, F2,
                                                      logcv, logits);
    k_norm<<<dim3(NN), dim3(256), 0, stream>>>(logits, out);
}